// Round 6
// baseline (189.112 us; speedup 1.0000x reference)
//
#include <hip/hip_runtime.h>
#include <math.h>

#define DEV __device__ __forceinline__

DEV float dot4(float4 a, float4 b){ return a.x*b.x + a.y*b.y + a.z*b.z + a.w*b.w; }

DEV float wave_sum(float v){
  #pragma unroll
  for (int off = 32; off; off >>= 1) v += __shfl_xor(v, off, 64);
  return v;
}

DEV float gelu_exact(float v){ return 0.5f * v * (1.f + erff(v * 0.70710678118654752f)); }

// K1: fused landmark-transpose + prob.
// Per (b,n) row: dist to 64 landmarks (lane=k), min-max norm, gaussian sim, row-normalize.
__global__ void __launch_bounds__(256) k_prob(const float* __restrict__ lm,
                                              const float* __restrict__ enc,
                                              float* __restrict__ prob){
  int t = threadIdx.x, lane = t & 63, wv = t >> 6;
  int row0 = blockIdx.x*8 + wv*2;
  __shared__ float4 ls[3072];                 // [col 0..47][k 0..63]
  const float4* L4 = (const float4*)lm;       // [64][192]
  const float4* X0 = (const float4*)(enc + (size_t)row0*768);
  const float4* X1 = X0 + 192;
  float dot0=0.f, dot1=0.f, xn0=0.f, xn1=0.f, ln=0.f;
  for (int c = 0; c < 4; ++c){
    if (c) __syncthreads();
    #pragma unroll
    for (int i = 0; i < 12; ++i){
      int idx = i*256 + t;
      int k = idx & 63, col = idx >> 6;
      ls[idx] = L4[k*192 + c*48 + col];       // contiguous LDS write, scattered L2 read
    }
    __syncthreads();
    #pragma unroll 8
    for (int hg = 0; hg < 48; ++hg){
      float4 l4 = ls[hg*64 + lane];           // contiguous across lanes: conflict-free
      float4 a = X0[c*48 + hg], b = X1[c*48 + hg];   // wave-uniform broadcast
      dot0 += dot4(a, l4); dot1 += dot4(b, l4);
      xn0  += dot4(a, a);  xn1  += dot4(b, b);
      ln   += dot4(l4, l4);                   // lane k's own landmark norm
    }
  }
  float d0 = sqrtf(fmaxf(xn0 + ln - 2.f*dot0, 0.f));
  float d1 = sqrtf(fmaxf(xn1 + ln - 2.f*dot1, 0.f));
  float mn0=d0, mx0=d0, mn1=d1, mx1=d1;
  #pragma unroll
  for (int off = 32; off; off >>= 1){
    mn0 = fminf(mn0, __shfl_xor(mn0, off, 64));
    mx0 = fmaxf(mx0, __shfl_xor(mx0, off, 64));
    mn1 = fminf(mn1, __shfl_xor(mn1, off, 64));
    mx1 = fmaxf(mx1, __shfl_xor(mx1, off, 64));
  }
  float nd0 = (d0 - mn0) / (mx0 - mn0 + 1e-6f);
  float nd1 = (d1 - mn1) / (mx1 - mn1 + 1e-6f);
  float s0 = expf(nd0*nd0 * (-1.f/0.18f));    // 2*d^2 = 2*0.3^2 = 0.18
  float s1 = expf(nd1*nd1 * (-1.f/0.18f));
  float sum0 = wave_sum(s0), sum1 = wave_sum(s1);
  prob[(size_t)row0*64 + lane]     = s0 / sum0;
  prob[(size_t)(row0+1)*64 + lane] = s1 / sum1;
}

// K2: out[b,k,h] = sum_n prob[b,n,k]*enc[b,n,h]; also mbar[b,h] = mean_k out[b,k,h].
__global__ void k_pool(const float* __restrict__ enc, const float* __restrict__ prob,
                       float* __restrict__ outp, float* __restrict__ mbar){
  int b = blockIdx.x / 48, ch = blockIdx.x % 48;
  int lane = threadIdx.x & 63, wv = threadIdx.x >> 6;
  int h0 = ch*16 + wv*4;
  const float* E = enc + (size_t)b*256*768 + h0;
  const float* P = prob + (size_t)b*256*64;
  float acc[4] = {0,0,0,0};
  #pragma unroll 4
  for (int n = 0; n < 256; ++n){
    float p = P[n*64 + lane];                              // coalesced
    float4 e0 = *(const float4*)(E + (size_t)n*768);       // broadcast
    acc[0] += p*e0.x; acc[1] += p*e0.y; acc[2] += p*e0.z; acc[3] += p*e0.w;
  }
  float* O = outp + ((size_t)b*64 + lane)*768 + h0;
  *(float4*)O = make_float4(acc[0],acc[1],acc[2],acc[3]);
  #pragma unroll
  for (int j = 0; j < 4; ++j){
    float v = wave_sum(acc[j]);
    if (lane == 0) mbar[(size_t)b*768 + h0 + j] = v * (1.f/64.f);
  }
}

// K3/4/5: o[b,j] = bias[j] + sum_i in[b,i]*W[j,i]; in is [8][768], one wave per j.
__global__ void k_vm768(const float* __restrict__ in, const float* __restrict__ W,
                        const float* __restrict__ bias, float* __restrict__ out){
  int lane = threadIdx.x & 63, wv = threadIdx.x >> 6;
  int j = blockIdx.x*4 + wv;
  const float4* Wr = (const float4*)(W + (size_t)j*768);
  const float4* IN = (const float4*)in;
  float acc[8] = {0,0,0,0,0,0,0,0};
  #pragma unroll
  for (int s = 0; s < 3; ++s){
    int ig = s*64 + lane;
    float4 w4 = Wr[ig];
    #pragma unroll
    for (int b = 0; b < 8; ++b) acc[b] += dot4(w4, IN[b*192 + ig]);
  }
  #pragma unroll
  for (int b = 0; b < 8; ++b){
    float v = wave_sum(acc[b]);
    if (lane == 0) out[b*768 + j] = v + bias[j];
  }
}

// K6: fc1 partials — barrier-free, LDS-free, kc-major.
// Grid = 32 kc-chunks (major) x 63 j-groups of 16 rows. Each wave owns 4 full
// j-rows over a 1536-float K-chunk: 24 W float4-loads issued up-front (never
// force-drained by any barrier), X read directly from L2 (kc-major grid keeps
// the 49 KB chunk hot; xcat fused on the fly as 2*outp + hx3). Wave-reduce,
// lanes 0-31 write 32 coalesced partials. No __syncthreads anywhere.
__global__ void __launch_bounds__(256) k_fc1s(const float* __restrict__ outp,
                                              const float* __restrict__ hx3,
                                              const float* __restrict__ W,
                                              float* __restrict__ part){
  int t = threadIdx.x, lane = t & 63, wv = t >> 6;
  int kc = blockIdx.x / 63, jg = blockIdx.x % 63;
  int j0 = jg*16 + wv*4;
  if (j0 >= 1000) return;                       // jg=62: waves 2,3 idle (8 tail rows)
  const float4* O4 = (const float4*)outp + kc*384;   // [b][12288] float4
  const float4* H4 = (const float4*)hx3;             // [b][192]
  const float4* W0 = (const float4*)W + (size_t)j0*12288 + kc*384;

  // 24 independent 16B W loads in flight per wave
  float4 w[4][6];
  #pragma unroll
  for (int r = 0; r < 4; ++r)
    #pragma unroll
    for (int s = 0; s < 6; ++s)
      w[r][s] = W0[(size_t)r*12288 + s*64 + lane];

  float acc[4][8];
  #pragma unroll
  for (int r = 0; r < 4; ++r)
    #pragma unroll
    for (int b = 0; b < 8; ++b) acc[r][b] = 0.f;

  #pragma unroll
  for (int s = 0; s < 6; ++s){
    int ig = s*64 + lane;                       // 0..383 within chunk
    int hm = ig - (ig >= 192 ? 192 : 0);        // (kc*384+ig) mod 192
    #pragma unroll
    for (int b = 0; b < 8; ++b){
      float4 o = O4[(size_t)b*12288 + ig];      // coalesced, L2-hot
      float4 g = H4[b*192 + hm];                // 6 KB, L1-resident
      float4 xv;
      xv.x = 2.f*o.x + g.x; xv.y = 2.f*o.y + g.y;
      xv.z = 2.f*o.z + g.z; xv.w = 2.f*o.w + g.w;
      acc[0][b] += dot4(w[0][s], xv);
      acc[1][b] += dot4(w[1][s], xv);
      acc[2][b] += dot4(w[2][s], xv);
      acc[3][b] += dot4(w[3][s], xv);
    }
  }

  // full wave reductions (all lanes end with the sum), then 32 coalesced stores
  float v = 0.f;
  #pragma unroll
  for (int r = 0; r < 4; ++r)
    #pragma unroll
    for (int b = 0; b < 8; ++b){
      float s = wave_sum(acc[r][b]);
      v = (lane == r*8 + b) ? s : v;            // static indices only (no scratch)
    }
  if (lane < 32)
    part[(size_t)kc*8000 + (size_t)j0*8 + lane] = v;   // [kc][j][b], contiguous 128B
}

// K7: fused kc-reduce + bias + gelu -> fc2 + gelu -> fc3. One block per batch b.
__global__ void __launch_bounds__(256) k_tail(const float* __restrict__ part,
                                              const float* __restrict__ fb1,
                                              const float* __restrict__ W2,
                                              const float* __restrict__ fb2,
                                              const float* __restrict__ W3,
                                              const float* __restrict__ fb3,
                                              float* __restrict__ out){
  int b = blockIdx.x, t = threadIdx.x, lane = t & 63, wv = t >> 6;
  __shared__ __align__(16) float x1s[1000];
  __shared__ float x2s[100];
  #pragma unroll
  for (int i = 0; i < 4; ++i){
    int j = i*256 + t;
    if (j < 1000){
      float v = fb1[j];
      #pragma unroll
      for (int kc = 0; kc < 32; ++kc)
        v += part[(size_t)kc*8000 + j*8 + b];
      x1s[j] = gelu_exact(v);
    }
  }
  __syncthreads();
  const float4* X4 = (const float4*)x1s;     // 250 float4
  for (int i = 0; i < 25; ++i){
    int m = wv*25 + i;
    const float4* Wr = (const float4*)(W2 + (size_t)m*1000);
    float acc = 0.f;
    #pragma unroll
    for (int s = 0; s < 4; ++s){
      int jg = s*64 + lane;
      if (jg < 250) acc += dot4(Wr[jg], X4[jg]);
    }
    acc = wave_sum(acc);
    if (lane == 0) x2s[m] = gelu_exact(acc + fb2[m]);
  }
  __syncthreads();
  if (t < 10){
    float acc = fb3[t];
    const float* Wr = W3 + t*100;
    #pragma unroll 4
    for (int m = 0; m < 100; ++m) acc += x2s[m]*Wr[m];
    out[b*10 + t] = acc;
  }
}

extern "C" void kernel_launch(void* const* d_in, const int* in_sizes, int n_in,
                              void* d_out, int out_size, void* d_ws, size_t ws_size,
                              hipStream_t stream){
  const float* enc = (const float*)d_in[0];
  const float* lm  = (const float*)d_in[1];
  // d_in[2] = alpha: provably unused — G = P dw P^T is strictly positive for any
  // alpha (dw diagonal = 1), so A=(G!=0) is all-ones and An = J/64.
  const float* w1  = (const float*)d_in[3];
  const float* b1  = (const float*)d_in[4];
  const float* w2  = (const float*)d_in[5];
  const float* b2  = (const float*)d_in[6];
  const float* w3  = (const float*)d_in[7];
  const float* b3  = (const float*)d_in[8];
  const float* fw1 = (const float*)d_in[9];
  const float* fb1 = (const float*)d_in[10];
  const float* fw2 = (const float*)d_in[11];
  const float* fb2 = (const float*)d_in[12];
  const float* fw3 = (const float*)d_in[13];
  const float* fb3 = (const float*)d_in[14];

  float* ws    = (float*)d_ws;
  float* prob  = ws;               // 131072
  float* outp  = prob  + 131072;   // 393216
  float* mbar  = outp  + 393216;   // 6144
  float* hx1   = mbar  + 6144;     // 6144
  float* hx2   = hx1   + 6144;     // 6144
  float* hx3   = hx2   + 6144;     // 6144
  float* part  = hx3   + 6144;     // 256000 (32 chunks x 8000)
  float* out   = (float*)d_out;

  k_prob <<<256, 256, 0, stream>>>(lm, enc, prob);
  k_pool <<<384, 256, 0, stream>>>(enc, prob, outp, mbar);
  k_vm768<<<192, 256, 0, stream>>>(mbar, w1, b1, hx1);
  k_vm768<<<192, 256, 0, stream>>>(hx1,  w2, b2, hx2);
  k_vm768<<<192, 256, 0, stream>>>(hx2,  w3, b3, hx3);
  k_fc1s <<<2016,256, 0, stream>>>(outp, hx3, fw1, part);
  k_tail <<<8,   256, 0, stream>>>(part, fb1, fw2, fb2, fw3, fb3, out);
}

// Round 8
// 178.759 us; speedup vs baseline: 1.0579x; 1.0579x over previous
//
#include <hip/hip_runtime.h>
#include <math.h>

#define DEV __device__ __forceinline__

DEV float dot4(float4 a, float4 b){ return a.x*b.x + a.y*b.y + a.z*b.z + a.w*b.w; }

DEV float wave_sum(float v){
  #pragma unroll
  for (int off = 32; off; off >>= 1) v += __shfl_xor(v, off, 64);
  return v;
}

DEV float gelu_exact(float v){ return 0.5f * v * (1.f + erff(v * 0.70710678118654752f)); }

// async global->LDS, 16B per lane: lds dest is wave-uniform base + lane*16,
// global src is per-lane (base + lane).
#define GL16(gsrc, ldst)                                                        \
  __builtin_amdgcn_global_load_lds(                                             \
      (const __attribute__((address_space(1))) void*)(gsrc),                    \
      (__attribute__((address_space(3))) void*)(ldst), 16, 0, 0)

// K1: fused landmark-transpose + prob.
__global__ void __launch_bounds__(256) k_prob(const float* __restrict__ lm,
                                              const float* __restrict__ enc,
                                              float* __restrict__ prob){
  int t = threadIdx.x, lane = t & 63, wv = t >> 6;
  int row0 = blockIdx.x*8 + wv*2;
  __shared__ float4 ls[3072];                 // [col 0..47][k 0..63]
  const float4* L4 = (const float4*)lm;       // [64][192]
  const float4* X0 = (const float4*)(enc + (size_t)row0*768);
  const float4* X1 = X0 + 192;
  float dot0=0.f, dot1=0.f, xn0=0.f, xn1=0.f, ln=0.f;
  for (int c = 0; c < 4; ++c){
    if (c) __syncthreads();
    #pragma unroll
    for (int i = 0; i < 12; ++i){
      int idx = i*256 + t;
      int k = idx & 63, col = idx >> 6;
      ls[idx] = L4[k*192 + c*48 + col];       // contiguous LDS write, scattered L2 read
    }
    __syncthreads();
    #pragma unroll 8
    for (int hg = 0; hg < 48; ++hg){
      float4 l4 = ls[hg*64 + lane];           // contiguous across lanes: conflict-free
      float4 a = X0[c*48 + hg], b = X1[c*48 + hg];   // wave-uniform broadcast
      dot0 += dot4(a, l4); dot1 += dot4(b, l4);
      xn0  += dot4(a, a);  xn1  += dot4(b, b);
      ln   += dot4(l4, l4);                   // lane k's own landmark norm
    }
  }
  float d0 = sqrtf(fmaxf(xn0 + ln - 2.f*dot0, 0.f));
  float d1 = sqrtf(fmaxf(xn1 + ln - 2.f*dot1, 0.f));
  float mn0=d0, mx0=d0, mn1=d1, mx1=d1;
  #pragma unroll
  for (int off = 32; off; off >>= 1){
    mn0 = fminf(mn0, __shfl_xor(mn0, off, 64));
    mx0 = fmaxf(mx0, __shfl_xor(mx0, off, 64));
    mn1 = fminf(mn1, __shfl_xor(mn1, off, 64));
    mx1 = fmaxf(mx1, __shfl_xor(mx1, off, 64));
  }
  float nd0 = (d0 - mn0) / (mx0 - mn0 + 1e-6f);
  float nd1 = (d1 - mn1) / (mx1 - mn1 + 1e-6f);
  float s0 = expf(nd0*nd0 * (-1.f/0.18f));    // 2*d^2 = 2*0.3^2 = 0.18
  float s1 = expf(nd1*nd1 * (-1.f/0.18f));
  float sum0 = wave_sum(s0), sum1 = wave_sum(s1);
  prob[(size_t)row0*64 + lane]     = s0 / sum0;
  prob[(size_t)(row0+1)*64 + lane] = s1 / sum1;
}

// K2: out[b,k,h] = sum_n prob[b,n,k]*enc[b,n,h]; also mbar[b,h] = mean_k out[b,k,h].
__global__ void k_pool(const float* __restrict__ enc, const float* __restrict__ prob,
                       float* __restrict__ outp, float* __restrict__ mbar){
  int b = blockIdx.x / 48, ch = blockIdx.x % 48;
  int lane = threadIdx.x & 63, wv = threadIdx.x >> 6;
  int h0 = ch*16 + wv*4;
  const float* E = enc + (size_t)b*256*768 + h0;
  const float* P = prob + (size_t)b*256*64;
  float acc[4] = {0,0,0,0};
  #pragma unroll 4
  for (int n = 0; n < 256; ++n){
    float p = P[n*64 + lane];                              // coalesced
    float4 e0 = *(const float4*)(E + (size_t)n*768);       // broadcast
    acc[0] += p*e0.x; acc[1] += p*e0.y; acc[2] += p*e0.z; acc[3] += p*e0.w;
  }
  float* O = outp + ((size_t)b*64 + lane)*768 + h0;
  *(float4*)O = make_float4(acc[0],acc[1],acc[2],acc[3]);
  #pragma unroll
  for (int j = 0; j < 4; ++j){
    float v = wave_sum(acc[j]);
    if (lane == 0) mbar[(size_t)b*768 + h0 + j] = v * (1.f/64.f);
  }
}

// K3/4/5: o[b,j] = bias[j] + sum_i in[b,i]*W[j,i]; in is [8][768], one wave per j.
__global__ void k_vm768(const float* __restrict__ in, const float* __restrict__ W,
                        const float* __restrict__ bias, float* __restrict__ out){
  int lane = threadIdx.x & 63, wv = threadIdx.x >> 6;
  int j = blockIdx.x*4 + wv;
  const float4* Wr = (const float4*)(W + (size_t)j*768);
  const float4* IN = (const float4*)in;
  float acc[8] = {0,0,0,0,0,0,0,0};
  #pragma unroll
  for (int s = 0; s < 3; ++s){
    int ig = s*64 + lane;
    float4 w4 = Wr[ig];
    #pragma unroll
    for (int b = 0; b < 8; ++b) acc[b] += dot4(w4, IN[b*192 + ig]);
  }
  #pragma unroll
  for (int b = 0; b < 8; ++b){
    float v = wave_sum(acc[b]);
    if (lane == 0) out[b*768 + j] = v + bias[j];
  }
}

// K5b: x[b, k*768+h] = 2*out[b,k,h] + hx3[b,h]  (plain buffer so fc1 can gload_lds it)
__global__ void k_xcat(const float* __restrict__ outp, const float* __restrict__ hx3,
                       float* __restrict__ x){
  int idx = blockIdx.x*256 + threadIdx.x;      // float4 index, 98304 total
  int h4 = idx % 192;
  int b  = idx / (192*64);
  float4 o = ((const float4*)outp)[idx];
  float4 g = ((const float4*)hx3)[b*192 + h4];
  float4 r;
  r.x = 2.f*o.x + g.x; r.y = 2.f*o.y + g.y; r.z = 2.f*o.z + g.z; r.w = 2.f*o.w + g.w;
  ((float4*)x)[idx] = r;
}

// K6: fc1 partials — W streamed via global_load_lds through a 3-deep LDS ring with
// counted vmcnt (never a full drain), ZERO barriers in the main loop (each wave
// consumes only the W rows it staged; X is shared but staged+barriered once).
// Grid = 32 kc (major) x 125 jg = 4000 blocks; 8 j-rows x 1536-float K-chunk.
// LDS = 49K (X) + 24K (W ring) -> 2 blocks/CU. Data-in-flight costs no VGPRs.
// NOTE (R7 bug): xcat batch stride is 12288 float4 (49152 floats), NOT 3072.
__global__ void __launch_bounds__(256) k_fc1s(const float* __restrict__ xcat,
                                              const float* __restrict__ W,
                                              float* __restrict__ part){
  int t = threadIdx.x, lane = t & 63, wv = t >> 6;
  int kc = blockIdx.x / 125, jg = blockIdx.x % 125;
  int j0 = jg*8;
  __shared__ float4 xs4[3072];        // [b][384]
  __shared__ float4 wb4[1536];        // ring [3][row 0..7][64]
  __shared__ float sp[64];
  int rA = 2*wv, rB = 2*wv + 1;
  const float4* X4 = (const float4*)xcat + kc*384 + lane;                 // + b*12288 + q*64
  const float4* WA = (const float4*)W + (size_t)(j0 + rA)*12288 + kc*384 + lane;
  const float4* WB = (const float4*)W + (size_t)(j0 + rB)*12288 + kc*384 + lane;

  // X: 12 gload_lds per wave (b = rA,rB ; q = 0..5); batch stride 12288 float4
  #pragma unroll
  for (int q = 0; q < 6; ++q){
    GL16(X4 + (size_t)rA*12288 + q*64, &xs4[rA*384 + q*64]);
    GL16(X4 + (size_t)rB*12288 + q*64, &xs4[rB*384 + q*64]);
  }
  // W phases 0,1 prefetch (2 instr per phase per wave)
  GL16(WA + 0*64, &wb4[0*512 + rA*64]);
  GL16(WB + 0*64, &wb4[0*512 + rB*64]);
  GL16(WA + 1*64, &wb4[1*512 + rA*64]);
  GL16(WB + 1*64, &wb4[1*512 + rB*64]);

  asm volatile("s_waitcnt vmcnt(4)" ::: "memory");   // 12 oldest (X) retired
  __syncthreads();                                    // X visible to all waves

  float acc0[8] = {0,0,0,0,0,0,0,0};
  float acc1[8] = {0,0,0,0,0,0,0,0};

#define FC1_PHASE(P, ISSUE, WAITSTR)                                       \
  {                                                                        \
    if ((ISSUE) >= 0){                                                     \
      GL16(WA + (ISSUE)*64, &wb4[((ISSUE)%3)*512 + rA*64]);                \
      GL16(WB + (ISSUE)*64, &wb4[((ISSUE)%3)*512 + rB*64]);                \
    }                                                                      \
    asm volatile(WAITSTR ::: "memory");                                    \
    float4 wA = wb4[((P)%3)*512 + rA*64 + lane];                           \
    float4 wB = wb4[((P)%3)*512 + rB*64 + lane];                           \
    _Pragma("unroll")                                                      \
    for (int b = 0; b < 8; ++b){                                           \
      float4 xv = xs4[b*384 + (P)*64 + lane];                              \
      acc0[b] += dot4(wA, xv);                                             \
      acc1[b] += dot4(wB, xv);                                             \
    }                                                                      \
  }

  FC1_PHASE(0, 2, "s_waitcnt vmcnt(4)")
  FC1_PHASE(1, 3, "s_waitcnt vmcnt(4)")
  FC1_PHASE(2, 4, "s_waitcnt vmcnt(4)")
  FC1_PHASE(3, 5, "s_waitcnt vmcnt(4)")
  FC1_PHASE(4, -1, "s_waitcnt vmcnt(2)")
  FC1_PHASE(5, -1, "s_waitcnt vmcnt(0)")
#undef FC1_PHASE

  // wave-reduce the 16 partials, stash, coalesced write-out
  #pragma unroll
  for (int b = 0; b < 8; ++b){
    float v0 = wave_sum(acc0[b]);
    float v1 = wave_sum(acc1[b]);
    if (lane == 0){ sp[rA*8 + b] = v0; sp[rB*8 + b] = v1; }
  }
  __syncthreads();
  if (t < 64)
    part[(size_t)kc*8000 + (size_t)j0*8 + t] = sp[t];   // [kc][j][b]
}

// K7: fused kc-reduce + bias + gelu -> fc2 + gelu -> fc3. One block per batch b.
__global__ void __launch_bounds__(256) k_tail(const float* __restrict__ part,
                                              const float* __restrict__ fb1,
                                              const float* __restrict__ W2,
                                              const float* __restrict__ fb2,
                                              const float* __restrict__ W3,
                                              const float* __restrict__ fb3,
                                              float* __restrict__ out){
  int b = blockIdx.x, t = threadIdx.x, lane = t & 63, wv = t >> 6;
  __shared__ __align__(16) float x1s[1000];
  __shared__ float x2s[100];
  #pragma unroll
  for (int i = 0; i < 4; ++i){
    int j = i*256 + t;
    if (j < 1000){
      float v = fb1[j];
      #pragma unroll
      for (int kc = 0; kc < 32; ++kc)
        v += part[(size_t)kc*8000 + j*8 + b];
      x1s[j] = gelu_exact(v);
    }
  }
  __syncthreads();
  const float4* X4 = (const float4*)x1s;     // 250 float4
  for (int i = 0; i < 25; ++i){
    int m = wv*25 + i;
    const float4* Wr = (const float4*)(W2 + (size_t)m*1000);
    float acc = 0.f;
    #pragma unroll
    for (int s = 0; s < 4; ++s){
      int jg = s*64 + lane;
      if (jg < 250) acc += dot4(Wr[jg], X4[jg]);
    }
    acc = wave_sum(acc);
    if (lane == 0) x2s[m] = gelu_exact(acc + fb2[m]);
  }
  __syncthreads();
  if (t < 10){
    float acc = fb3[t];
    const float* Wr = W3 + t*100;
    #pragma unroll 4
    for (int m = 0; m < 100; ++m) acc += x2s[m]*Wr[m];
    out[b*10 + t] = acc;
  }
}

extern "C" void kernel_launch(void* const* d_in, const int* in_sizes, int n_in,
                              void* d_out, int out_size, void* d_ws, size_t ws_size,
                              hipStream_t stream){
  const float* enc = (const float*)d_in[0];
  const float* lm  = (const float*)d_in[1];
  // d_in[2] = alpha: provably unused — G = P dw P^T is strictly positive for any
  // alpha (dw diagonal = 1), so A=(G!=0) is all-ones and An = J/64.
  const float* w1  = (const float*)d_in[3];
  const float* b1  = (const float*)d_in[4];
  const float* w2  = (const float*)d_in[5];
  const float* b2  = (const float*)d_in[6];
  const float* w3  = (const float*)d_in[7];
  const float* b3  = (const float*)d_in[8];
  const float* fw1 = (const float*)d_in[9];
  const float* fb1 = (const float*)d_in[10];
  const float* fw2 = (const float*)d_in[11];
  const float* fb2 = (const float*)d_in[12];
  const float* fw3 = (const float*)d_in[13];
  const float* fb3 = (const float*)d_in[14];

  float* ws    = (float*)d_ws;
  float* prob  = ws;               // 131072
  float* outp  = prob  + 131072;   // 393216
  float* mbar  = outp  + 393216;   // 6144
  float* hx1   = mbar  + 6144;     // 6144
  float* hx2   = hx1   + 6144;     // 6144
  float* hx3   = hx2   + 6144;     // 6144
  float* xcat  = hx3   + 6144;     // 393216
  float* part  = xcat  + 393216;   // 256000 (32 chunks x 8000)
  float* out   = (float*)d_out;

  k_prob <<<256, 256, 0, stream>>>(lm, enc, prob);
  k_pool <<<384, 256, 0, stream>>>(enc, prob, outp, mbar);
  k_vm768<<<192, 256, 0, stream>>>(mbar, w1, b1, hx1);
  k_vm768<<<192, 256, 0, stream>>>(hx1,  w2, b2, hx2);
  k_vm768<<<192, 256, 0, stream>>>(hx2,  w3, b3, hx3);
  k_xcat <<<384, 256, 0, stream>>>(outp, hx3, xcat);
  k_fc1s <<<4000,256, 0, stream>>>(xcat, fw1, part);
  k_tail <<<8,   256, 0, stream>>>(part, fb1, fw2, fb2, fw3, fb3, out);
}

// Round 9
// 166.005 us; speedup vs baseline: 1.1392x; 1.0768x over previous
//
#include <hip/hip_runtime.h>
#include <math.h>

#define DEV __device__ __forceinline__

DEV float dot4(float4 a, float4 b){ return a.x*b.x + a.y*b.y + a.z*b.z + a.w*b.w; }

DEV float wave_sum(float v){
  #pragma unroll
  for (int off = 32; off; off >>= 1) v += __shfl_xor(v, off, 64);
  return v;
}

DEV float gelu_exact(float v){ return 0.5f * v * (1.f + erff(v * 0.70710678118654752f)); }

// K1: fused landmark-transpose + prob.
// Per (b,n) row: dist to 64 landmarks (lane=k), min-max norm, gaussian sim, row-normalize.
__global__ void __launch_bounds__(256) k_prob(const float* __restrict__ lm,
                                              const float* __restrict__ enc,
                                              float* __restrict__ prob){
  int t = threadIdx.x, lane = t & 63, wv = t >> 6;
  int row0 = blockIdx.x*8 + wv*2;
  __shared__ float4 ls[3072];                 // [col 0..47][k 0..63]
  const float4* L4 = (const float4*)lm;       // [64][192]
  const float4* X0 = (const float4*)(enc + (size_t)row0*768);
  const float4* X1 = X0 + 192;
  float dot0=0.f, dot1=0.f, xn0=0.f, xn1=0.f, ln=0.f;
  for (int c = 0; c < 4; ++c){
    if (c) __syncthreads();
    #pragma unroll
    for (int i = 0; i < 12; ++i){
      int idx = i*256 + t;
      int k = idx & 63, col = idx >> 6;
      ls[idx] = L4[k*192 + c*48 + col];       // contiguous LDS write, scattered L2 read
    }
    __syncthreads();
    #pragma unroll 8
    for (int hg = 0; hg < 48; ++hg){
      float4 l4 = ls[hg*64 + lane];           // contiguous across lanes: conflict-free
      float4 a = X0[c*48 + hg], b = X1[c*48 + hg];   // wave-uniform broadcast
      dot0 += dot4(a, l4); dot1 += dot4(b, l4);
      xn0  += dot4(a, a);  xn1  += dot4(b, b);
      ln   += dot4(l4, l4);                   // lane k's own landmark norm
    }
  }
  float d0 = sqrtf(fmaxf(xn0 + ln - 2.f*dot0, 0.f));
  float d1 = sqrtf(fmaxf(xn1 + ln - 2.f*dot1, 0.f));
  float mn0=d0, mx0=d0, mn1=d1, mx1=d1;
  #pragma unroll
  for (int off = 32; off; off >>= 1){
    mn0 = fminf(mn0, __shfl_xor(mn0, off, 64));
    mx0 = fmaxf(mx0, __shfl_xor(mx0, off, 64));
    mn1 = fminf(mn1, __shfl_xor(mn1, off, 64));
    mx1 = fmaxf(mx1, __shfl_xor(mx1, off, 64));
  }
  float nd0 = (d0 - mn0) / (mx0 - mn0 + 1e-6f);
  float nd1 = (d1 - mn1) / (mx1 - mn1 + 1e-6f);
  float s0 = expf(nd0*nd0 * (-1.f/0.18f));    // 2*d^2 = 2*0.3^2 = 0.18
  float s1 = expf(nd1*nd1 * (-1.f/0.18f));
  float sum0 = wave_sum(s0), sum1 = wave_sum(s1);
  prob[(size_t)row0*64 + lane]     = s0 / sum0;
  prob[(size_t)(row0+1)*64 + lane] = s1 / sum1;
}

// K2: out[b,k,h] = sum_n prob[b,n,k]*enc[b,n,h]; also mbar[b,h] = mean_k out[b,k,h].
__global__ void k_pool(const float* __restrict__ enc, const float* __restrict__ prob,
                       float* __restrict__ outp, float* __restrict__ mbar){
  int b = blockIdx.x / 48, ch = blockIdx.x % 48;
  int lane = threadIdx.x & 63, wv = threadIdx.x >> 6;
  int h0 = ch*16 + wv*4;
  const float* E = enc + (size_t)b*256*768 + h0;
  const float* P = prob + (size_t)b*256*64;
  float acc[4] = {0,0,0,0};
  #pragma unroll 8
  for (int n = 0; n < 256; ++n){
    float p = P[n*64 + lane];                              // coalesced
    float4 e0 = *(const float4*)(E + (size_t)n*768);       // broadcast
    acc[0] += p*e0.x; acc[1] += p*e0.y; acc[2] += p*e0.z; acc[3] += p*e0.w;
  }
  float* O = outp + ((size_t)b*64 + lane)*768 + h0;
  *(float4*)O = make_float4(acc[0],acc[1],acc[2],acc[3]);
  #pragma unroll
  for (int j = 0; j < 4; ++j){
    float v = wave_sum(acc[j]);
    if (lane == 0) mbar[(size_t)b*768 + h0 + j] = v * (1.f/64.f);
  }
}

// K3/4/5: o[b,j] = bias[j] + sum_i in[b,i]*W[j,i]; in is [8][768], one wave per j.
__global__ void k_vm768(const float* __restrict__ in, const float* __restrict__ W,
                        const float* __restrict__ bias, float* __restrict__ out){
  int lane = threadIdx.x & 63, wv = threadIdx.x >> 6;
  int j = blockIdx.x*4 + wv;
  const float4* Wr = (const float4*)(W + (size_t)j*768);
  const float4* IN = (const float4*)in;
  float acc[8] = {0,0,0,0,0,0,0,0};
  #pragma unroll
  for (int s = 0; s < 3; ++s){
    int ig = s*64 + lane;
    float4 w4 = Wr[ig];
    #pragma unroll
    for (int b = 0; b < 8; ++b) acc[b] += dot4(w4, IN[b*192 + ig]);
  }
  #pragma unroll
  for (int b = 0; b < 8; ++b){
    float v = wave_sum(acc[b]);
    if (lane == 0) out[b*768 + j] = v + bias[j];
  }
}

// K6: fc1 direct — R1's proven long-K geometry + on-the-fly xcat + direct y1 write.
// Grid = 250 blocks x 4 waves; block owns 4 full j-rows; wave wv covers the
// K-quarter [wv*12288, (wv+1)*12288) in 48 steps of 64 float4 (12 coalesced 1KB
// loads per step, ~24 in flight with unroll 2). No K-split, no barriers in the
// loop, no LDS staging: X (1.57 MB) is read in lockstep by all blocks -> L2-hot;
// W streams its 196.6 MB exactly once (L3/HBM). x = 2*outp + hx3 fused on the
// fly (hx3 float4-index = (s%3)*64+lane, L1-resident).
__global__ void __launch_bounds__(256, 1) k_fc1(const float* __restrict__ outp,
                                                const float* __restrict__ hx3,
                                                const float* __restrict__ W,
                                                float* __restrict__ y1){
  int t = threadIdx.x, lane = t & 63, wv = t >> 6;
  int j0 = blockIdx.x*4;
  const float4* O4 = (const float4*)outp;           // [8][12288]
  const float4* H4 = (const float4*)hx3;            // [8][192]
  const float4* Wr0 = (const float4*)W + (size_t)(j0+0)*12288 + wv*3072;
  const float4* Wr1 = Wr0 + 12288;
  const float4* Wr2 = Wr0 + 2*12288;
  const float4* Wr3 = Wr0 + 3*12288;
  int base = wv*3072;
  float acc[4][8];
  #pragma unroll
  for (int r = 0; r < 4; ++r)
    #pragma unroll
    for (int b = 0; b < 8; ++b) acc[r][b] = 0.f;

  #pragma unroll 2
  for (int s = 0; s < 48; ++s){
    int io = s*64 + lane;
    int ig = base + io;
    int hg = (s % 3)*64 + lane;                     // (wv*3072+s*64) mod 192 == (s%3)*64
    float4 w0 = Wr0[io], w1 = Wr1[io], w2 = Wr2[io], w3 = Wr3[io];
    #pragma unroll
    for (int b = 0; b < 8; ++b){
      float4 o = O4[(size_t)b*12288 + ig];          // coalesced, L2-hot
      float4 g = H4[b*192 + hg];                    // 6 KB, L1-resident
      float4 xv;
      xv.x = 2.f*o.x + g.x; xv.y = 2.f*o.y + g.y;
      xv.z = 2.f*o.z + g.z; xv.w = 2.f*o.w + g.w;
      acc[0][b] += dot4(w0, xv);
      acc[1][b] += dot4(w1, xv);
      acc[2][b] += dot4(w2, xv);
      acc[3][b] += dot4(w3, xv);
    }
  }

  __shared__ float sp[4][32];
  float v = 0.f;
  #pragma unroll
  for (int r = 0; r < 4; ++r)
    #pragma unroll
    for (int b = 0; b < 8; ++b){
      float s = wave_sum(acc[r][b]);
      v = (lane == r*8 + b) ? s : v;                // static lane select, stays in regs
    }
  if (lane < 32) sp[wv][lane] = v;
  __syncthreads();
  if (t < 32){
    int jj = t >> 3, b = t & 7;
    y1[b*1000 + j0 + jj] = sp[0][t] + sp[1][t] + sp[2][t] + sp[3][t];
  }
}

// K7: fc2 at 32 blocks (b x 4 m-chunks): gelu(y1+fb1) staged in LDS, 25 m per block.
__global__ void __launch_bounds__(256) k_fc2(const float* __restrict__ y1,
                                             const float* __restrict__ fb1,
                                             const float* __restrict__ W2,
                                             const float* __restrict__ fb2,
                                             float* __restrict__ x2){
  int b = blockIdx.x >> 2, mc = blockIdx.x & 3;
  int t = threadIdx.x, lane = t & 63, wv = t >> 6;
  __shared__ __align__(16) float x1s[1000];
  #pragma unroll
  for (int i = 0; i < 4; ++i){
    int j = i*256 + t;
    if (j < 1000) x1s[j] = gelu_exact(y1[b*1000 + j] + fb1[j]);
  }
  __syncthreads();
  const float4* X4 = (const float4*)x1s;     // 250 float4
  for (int i = wv; i < 25; i += 4){
    int m = mc*25 + i;
    const float4* Wr = (const float4*)(W2 + (size_t)m*1000);
    float acc = 0.f;
    #pragma unroll
    for (int s = 0; s < 4; ++s){
      int jg = s*64 + lane;
      if (jg < 250) acc += dot4(Wr[jg], X4[jg]);
    }
    acc = wave_sum(acc);
    if (lane == 0) x2[b*100 + m] = gelu_exact(acc + fb2[m]);
  }
}

// K8: out[b,c] = x2[b,:] . fc3_w[c,:] + fc3_b[c]
__global__ void k_fc3(const float* __restrict__ x2, const float* __restrict__ W,
                      const float* __restrict__ bias, float* __restrict__ out){
  int t = threadIdx.x;
  if (t < 80){
    int b = t/10, c = t%10;
    float acc = bias[c];
    #pragma unroll 4
    for (int m = 0; m < 100; ++m) acc += x2[b*100+m] * W[c*100+m];
    out[t] = acc;
  }
}

extern "C" void kernel_launch(void* const* d_in, const int* in_sizes, int n_in,
                              void* d_out, int out_size, void* d_ws, size_t ws_size,
                              hipStream_t stream){
  const float* enc = (const float*)d_in[0];
  const float* lm  = (const float*)d_in[1];
  // d_in[2] = alpha: provably unused — G = P dw P^T is strictly positive for any
  // alpha (dw diagonal = 1), so A=(G!=0) is all-ones and An = J/64.
  const float* w1  = (const float*)d_in[3];
  const float* b1  = (const float*)d_in[4];
  const float* w2  = (const float*)d_in[5];
  const float* b2  = (const float*)d_in[6];
  const float* w3  = (const float*)d_in[7];
  const float* b3  = (const float*)d_in[8];
  const float* fw1 = (const float*)d_in[9];
  const float* fb1 = (const float*)d_in[10];
  const float* fw2 = (const float*)d_in[11];
  const float* fb2 = (const float*)d_in[12];
  const float* fw3 = (const float*)d_in[13];
  const float* fb3 = (const float*)d_in[14];

  float* ws    = (float*)d_ws;
  float* prob  = ws;               // 131072
  float* outp  = prob  + 131072;   // 393216
  float* mbar  = outp  + 393216;   // 6144
  float* hx1   = mbar  + 6144;     // 6144
  float* hx2   = hx1   + 6144;     // 6144
  float* hx3   = hx2   + 6144;     // 6144
  float* y1    = hx3   + 6144;     // 8000
  float* x2    = y1    + 8000;     // 800
  float* out   = (float*)d_out;

  k_prob <<<256, 256, 0, stream>>>(lm, enc, prob);
  k_pool <<<384, 256, 0, stream>>>(enc, prob, outp, mbar);
  k_vm768<<<192, 256, 0, stream>>>(mbar, w1, b1, hx1);
  k_vm768<<<192, 256, 0, stream>>>(hx1,  w2, b2, hx2);
  k_vm768<<<192, 256, 0, stream>>>(hx2,  w3, b3, hx3);
  k_fc1  <<<250, 256, 0, stream>>>(outp, hx3, fw1, y1);
  k_fc2  <<<32,  256, 0, stream>>>(y1, fb1, fw2, fb2, x2);
  k_fc3  <<<1,   128, 0, stream>>>(x2, fw3, fb3, out);
}